// Round 24
// baseline (345.301 us; speedup 1.0000x reference)
//
#include <hip/hip_runtime.h>
#include <math.h>

#define N_NODES 50000
#define N_EDGES 500000
#define NLAYERS 6
#define NEG_SLOPE 0.2f
#define LN_EPS 1e-5f
#define SCAN_B 1024
#define NSCAN_BLOCKS ((N_NODES + SCAN_B - 1) / SCAN_B)  // 49
#define LOG2E 1.4426950408889634f

typedef __attribute__((ext_vector_type(8))) short short8;
typedef __attribute__((ext_vector_type(4))) float f32x4;

__device__ __forceinline__ float wave_sum64(float v) {
#pragma unroll
    for (int m = 32; m >= 1; m >>= 1) v += __shfl_xor(v, m, 64);
    return v;
}

__device__ __forceinline__ int wave_incl_scan(int v, int lane) {
#pragma unroll
    for (int offs = 1; offs < 64; offs <<= 1) {
        int t = __shfl_up(v, offs, 64);
        if (lane >= offs) v += t;
    }
    return v;
}

__device__ __forceinline__ unsigned bf16_rne(float v) {
    unsigned u = __float_as_uint(v);
    return (u + 0x7fffu + ((u >> 16) & 1u)) >> 16;
}

__device__ __forceinline__ float fast_exp2(float x) {
    float r;
    asm("v_exp_f32 %0, %1" : "=v"(r) : "v"(x));
    return r;
}

__device__ __forceinline__ float4 bf4_to_f4(ushort4 u) {
    float4 r;
    r.x = __uint_as_float((unsigned)u.x << 16);
    r.y = __uint_as_float((unsigned)u.y << 16);
    r.z = __uint_as_float((unsigned)u.z << 16);
    r.w = __uint_as_float((unsigned)u.w << 16);
    return r;
}

// ---------------- CSR build (identity node order) ----------------
__global__ void count_deg(const int* __restrict__ dst, int* __restrict__ deg) {
    int i = blockIdx.x * blockDim.x + threadIdx.x;
    if (i < N_EDGES) atomicAdd(&deg[dst[i]], 1);
}

__global__ void scan1(const int* __restrict__ deg, int* __restrict__ row_ptr,
                      int* __restrict__ bsum) {
    __shared__ int wtot[16];
    int t = threadIdx.x;
    int i = blockIdx.x * SCAN_B + t;
    int lane = t & 63, wv = t >> 6;
    int v = (i < N_NODES) ? deg[i] : 0;
    int incl = wave_incl_scan(v, lane);
    if (lane == 63) wtot[wv] = incl;
    __syncthreads();
    if (wv == 0) {
        int wval = (lane < 16) ? wtot[lane] : 0;
        int ws = wave_incl_scan(wval, lane);
        if (lane < 16) wtot[lane] = ws - wval;
    }
    __syncthreads();
    int excl = incl - v + wtot[wv];
    if (i < N_NODES) row_ptr[i] = excl;
    if (t == SCAN_B - 1) bsum[blockIdx.x] = excl + v;
}

__global__ void scan3(int* __restrict__ row_ptr, const int* __restrict__ bsum,
                      int* __restrict__ pos) {
    __shared__ int boff_s;
    int t = threadIdx.x;
    if (t < 64) {
        int v = (t < NSCAN_BLOCKS && t < (int)blockIdx.x) ? bsum[t] : 0;
#pragma unroll
        for (int m = 32; m >= 1; m >>= 1) v += __shfl_xor(v, m, 64);
        if (t == 0) boff_s = v;
    }
    __syncthreads();
    int i = blockIdx.x * SCAN_B + t;
    if (i < N_NODES) {
        int r = row_ptr[i] + boff_s;
        row_ptr[i] = r;
        pos[i] = r;
    }
    if (i == 0) row_ptr[N_NODES] = N_EDGES;
}

__global__ void scatter_edges(const int* __restrict__ dst, const int* __restrict__ src,
                              int* __restrict__ pos, int* __restrict__ srcs) {
    int i = blockIdx.x * blockDim.x + threadIdx.x;
    if (i < N_EDGES) {
        int p = atomicAdd(&pos[dst[i]], 1);
        srcs[p] = src[i];
    }
}

// ---------------- pack 13 64x64 weight matrices into MFMA B-fragment order -------------
__global__ void pack_w(const float* __restrict__ w_in, const float* __restrict__ w_src,
                       const float* __restrict__ w_dst, unsigned short* __restrict__ wpk_hi,
                       unsigned short* __restrict__ wpk_lo) {
    int b = blockIdx.x;
    const float* W = (b == 0) ? w_in
                              : (b <= 6 ? w_src + (size_t)(b - 1) * 4096
                                        : w_dst + (size_t)(b - 7) * 4096);
    unsigned short* hi = wpk_hi + (size_t)b * 4096;
    unsigned short* lo = wpk_lo + (size_t)b * 4096;
    for (int idx = threadIdx.x; idx < 4096; idx += 256) {
        int t = idx >> 10;
        int s = (idx >> 9) & 1;
        int l = (idx >> 3) & 63;
        int j = idx & 7;
        int row = s * 32 + (l >> 4) * 8 + j;
        int col = t * 16 + (l & 15);
        float v = W[row * 64 + col];
        unsigned rh = bf16_rne(v);
        float hf = __uint_as_float(rh << 16);
        unsigned rl = bf16_rne(v - hf);
        hi[idx] = (unsigned short)rh;
        lo[idx] = (unsigned short)rl;
    }
}

// load 8 fp32 and split into bf16 hi/lo fragments (global or LDS pointer)
__device__ __forceinline__ void load_split8(const float* p, short8& hi, short8& lo) {
    float4 x0 = *(const float4*)p;
    float4 x1 = *(const float4*)(p + 4);
    float v[8] = {x0.x, x0.y, x0.z, x0.w, x1.x, x1.y, x1.z, x1.w};
#pragma unroll
    for (int j = 0; j < 8; ++j) {
        unsigned rh = bf16_rne(v[j]);
        float hf = __uint_as_float(rh << 16);
        unsigned rl = bf16_rne(v[j] - hf);
        hi[j] = (short)rh;
        lo[j] = (short)rl;
    }
}

// 16 output rows x 64 cols via 3-MFMA split-bf16 (fp32-accurate)
__device__ __forceinline__ void mfma_16rows(const short8 ah0, const short8 ah1, const short8 al0,
                                            const short8 al1,
                                            const unsigned short* __restrict__ whi,
                                            const unsigned short* __restrict__ wlo, int lane,
                                            f32x4 acc[4]) {
#pragma unroll
    for (int t = 0; t < 4; ++t) {
#pragma unroll
        for (int s = 0; s < 2; ++s) {
            const size_t boff = ((size_t)((t * 2 + s) * 64 + lane)) * 8;
            short8 bh = *(const short8*)(whi + boff);
            short8 bl = *(const short8*)(wlo + boff);
            short8 a_h = s ? ah1 : ah0;
            short8 a_l = s ? al1 : al0;
            acc[t] = __builtin_amdgcn_mfma_f32_16x16x32_bf16(a_h, bh, acc[t], 0, 0, 0);
            acc[t] = __builtin_amdgcn_mfma_f32_16x16x32_bf16(a_l, bh, acc[t], 0, 0, 0);
            acc[t] = __builtin_amdgcn_mfma_f32_16x16x32_bf16(a_h, bl, acc[t], 0, 0, 0);
        }
    }
}

// ---------------- input projection + FUSED layer-0 dual projection (proven) ------------
__global__ void mfma_in_proj(const float* __restrict__ X,
                             const unsigned short* __restrict__ whi,
                             const unsigned short* __restrict__ wlo,
                             const float* __restrict__ bias, float* __restrict__ H,
                             const unsigned short* __restrict__ wshi,
                             const unsigned short* __restrict__ wslo,
                             const float* __restrict__ bs,
                             const unsigned short* __restrict__ wdhi,
                             const unsigned short* __restrict__ wdlo,
                             const float* __restrict__ bd, unsigned short* __restrict__ FS,
                             unsigned short* __restrict__ FD) {
    __shared__ float tr[4][16 * 64];
    int lane = threadIdx.x & 63, wv = threadIdx.x >> 6;
    int R = blockIdx.x * 64 + wv * 16;
    int arow = min(R + (lane & 15), N_NODES - 1);
    const float* p = X + (size_t)arow * 64 + (lane >> 4) * 8;
    short8 ah0, ah1, al0, al1;
    load_split8(p, ah0, al0);
    load_split8(p + 32, ah1, al1);
    f32x4 acc[4];
    f32x4 z = {0.f, 0.f, 0.f, 0.f};
#pragma unroll
    for (int t = 0; t < 4; ++t) acc[t] = z;
    mfma_16rows(ah0, ah1, al0, al1, whi, wlo, lane, acc);
    int crow = R + (lane >> 4) * 4;
    int lrow0 = (lane >> 4) * 4;
#pragma unroll
    for (int t = 0; t < 4; ++t) {
        int col = t * 16 + (lane & 15);
        float bv = bias[col];
#pragma unroll
        for (int r = 0; r < 4; ++r) {
            int row = crow + r;
            float v = acc[t][r] + bv;
            if (row < N_NODES) H[(size_t)row * 64 + col] = v;
            tr[wv][(lrow0 + r) * 64 + col] = v;  // wave-private LDS transpose
        }
    }
    load_split8(&tr[wv][(lane & 15) * 64 + (lane >> 4) * 8], ah0, al0);
    load_split8(&tr[wv][(lane & 15) * 64 + 32 + (lane >> 4) * 8], ah1, al1);
    f32x4 accS[4], accD[4];
#pragma unroll
    for (int t = 0; t < 4; ++t) {
        accS[t] = z;
        accD[t] = z;
    }
    mfma_16rows(ah0, ah1, al0, al1, wshi, wslo, lane, accS);
    mfma_16rows(ah0, ah1, al0, al1, wdhi, wdlo, lane, accD);
#pragma unroll
    for (int t = 0; t < 4; ++t) {
        int col = t * 16 + (lane & 15);
        float bsv = bs[col], bdv = bd[col];
#pragma unroll
        for (int r = 0; r < 4; ++r) {
            int row = crow + r;
            if (row < N_NODES) {
                FS[(size_t)row * 64 + col] = (unsigned short)bf16_rne(accS[t][r] + bsv);
                FD[(size_t)row * 64 + col] = (unsigned short)bf16_rne(accD[t][r] + bdv);
            }
        }
    }
}

// ---------------- dual projection, 2 C-tiles per wave, shared B-fragment loads ---------
__global__ void mfma_dual(const float* __restrict__ X, const unsigned short* __restrict__ wshi,
                          const unsigned short* __restrict__ wslo, const float* __restrict__ bs,
                          const unsigned short* __restrict__ wdhi,
                          const unsigned short* __restrict__ wdlo, const float* __restrict__ bd,
                          unsigned short* __restrict__ FS, unsigned short* __restrict__ FD) {
    int lane = threadIdx.x & 63, wv = threadIdx.x >> 6;
    int R = blockIdx.x * 128 + wv * 32;
    int arow0 = min(R + (lane & 15), N_NODES - 1);
    int arow1 = min(R + 16 + (lane & 15), N_NODES - 1);
    const float* p0 = X + (size_t)arow0 * 64 + (lane >> 4) * 8;
    const float* p1 = X + (size_t)arow1 * 64 + (lane >> 4) * 8;
    short8 a0h0, a0h1, a0l0, a0l1, a1h0, a1h1, a1l0, a1l1;
    load_split8(p0, a0h0, a0l0);
    load_split8(p0 + 32, a0h1, a0l1);
    load_split8(p1, a1h0, a1l0);
    load_split8(p1 + 32, a1h1, a1l1);
    f32x4 aS0[4], aD0[4], aS1[4], aD1[4];
    f32x4 z = {0.f, 0.f, 0.f, 0.f};
#pragma unroll
    for (int t = 0; t < 4; ++t) {
        aS0[t] = z;
        aD0[t] = z;
        aS1[t] = z;
        aD1[t] = z;
    }
#pragma unroll
    for (int t = 0; t < 4; ++t) {
#pragma unroll
        for (int s = 0; s < 2; ++s) {
            const size_t boff = ((size_t)((t * 2 + s) * 64 + lane)) * 8;
            short8 bsh = *(const short8*)(wshi + boff);
            short8 bsl = *(const short8*)(wslo + boff);
            short8 bdh = *(const short8*)(wdhi + boff);
            short8 bdl = *(const short8*)(wdlo + boff);
            short8 A0h = s ? a0h1 : a0h0, A0l = s ? a0l1 : a0l0;
            short8 A1h = s ? a1h1 : a1h0, A1l = s ? a1l1 : a1l0;
            aS0[t] = __builtin_amdgcn_mfma_f32_16x16x32_bf16(A0h, bsh, aS0[t], 0, 0, 0);
            aS0[t] = __builtin_amdgcn_mfma_f32_16x16x32_bf16(A0l, bsh, aS0[t], 0, 0, 0);
            aS0[t] = __builtin_amdgcn_mfma_f32_16x16x32_bf16(A0h, bsl, aS0[t], 0, 0, 0);
            aS1[t] = __builtin_amdgcn_mfma_f32_16x16x32_bf16(A1h, bsh, aS1[t], 0, 0, 0);
            aS1[t] = __builtin_amdgcn_mfma_f32_16x16x32_bf16(A1l, bsh, aS1[t], 0, 0, 0);
            aS1[t] = __builtin_amdgcn_mfma_f32_16x16x32_bf16(A1h, bsl, aS1[t], 0, 0, 0);
            aD0[t] = __builtin_amdgcn_mfma_f32_16x16x32_bf16(A0h, bdh, aD0[t], 0, 0, 0);
            aD0[t] = __builtin_amdgcn_mfma_f32_16x16x32_bf16(A0l, bdh, aD0[t], 0, 0, 0);
            aD0[t] = __builtin_amdgcn_mfma_f32_16x16x32_bf16(A0h, bdl, aD0[t], 0, 0, 0);
            aD1[t] = __builtin_amdgcn_mfma_f32_16x16x32_bf16(A1h, bdh, aD1[t], 0, 0, 0);
            aD1[t] = __builtin_amdgcn_mfma_f32_16x16x32_bf16(A1l, bdh, aD1[t], 0, 0, 0);
            aD1[t] = __builtin_amdgcn_mfma_f32_16x16x32_bf16(A1h, bdl, aD1[t], 0, 0, 0);
        }
    }
    int crow0 = R + (lane >> 4) * 4;
    int crow1 = R + 16 + (lane >> 4) * 4;
#pragma unroll
    for (int t = 0; t < 4; ++t) {
        int col = t * 16 + (lane & 15);
        float bsv = bs[col], bdv = bd[col];
#pragma unroll
        for (int r = 0; r < 4; ++r) {
            int row0 = crow0 + r;
            if (row0 < N_NODES) {
                FS[(size_t)row0 * 64 + col] = (unsigned short)bf16_rne(aS0[t][r] + bsv);
                FD[(size_t)row0 * 64 + col] = (unsigned short)bf16_rne(aD0[t][r] + bdv);
            }
            int row1 = crow1 + r;
            if (row1 < N_NODES) {
                FS[(size_t)row1 * 64 + col] = (unsigned short)bf16_rne(aS1[t][r] + bsv);
                FD[(size_t)row1 * 64 + col] = (unsigned short)bf16_rne(aD1[t][r] + bdv);
            }
        }
    }
}

// ---------------- fused per-node: quarter-wave, no-max softmax, bf16 fs+fd -------------
#define WPB 4  // waves per block, 1 node per wave
__global__ void node_fused_kernel(const unsigned short* __restrict__ fs,
                                  const unsigned short* __restrict__ fd,
                                  const int* __restrict__ row_ptr, const int* __restrict__ srcs,
                                  const float* __restrict__ attn, const float* __restrict__ gamma,
                                  const float* __restrict__ beta, float* __restrict__ h) {
    __shared__ float xpose[WPB][64];
    int lane = threadIdx.x & 63;
    int wv = threadIdx.x >> 6;
    int q = lane >> 4;
    int ql = lane & 15;
    int f0 = ql << 2;
    int n = blockIdx.x * WPB + wv;
    if (n >= N_NODES) return;
    float gL = gamma[lane], bL = beta[lane];
    float hval = h[(size_t)n * 64 + lane];  // coalesced stream
    float4 a4 = *(const float4*)&attn[f0];
    a4.x *= LOG2E;
    a4.y *= LOG2E;
    a4.z *= LOG2E;
    a4.w *= LOG2E;
    int beg = row_ptr[n], end = row_ptr[n + 1];
    int deg = end - beg;
    float4 fd4 = bf4_to_f4(*(const ushort4*)&fd[(size_t)n * 64 + f0]);
    float d = 0.f;
    float4 acc = make_float4(0.f, 0.f, 0.f, 0.f);
    for (int c0 = 0; c0 < deg; c0 += 64) {
        int cl = min(64, deg - c0);
        int sv = (lane < cl) ? srcs[beg + c0 + lane] : 0;
        int nt = (cl + 3) >> 2;
        ushort4 rowA = make_ushort4(0, 0, 0, 0), rowB = rowA;
        int sid0 = __shfl(sv, q, 64);
        if (q < cl) rowA = *(const ushort4*)&fs[(size_t)sid0 * 64 + f0];
        int sid1 = __shfl(sv, (4 + q) & 63, 64);
        if (4 + q < cl) rowB = *(const ushort4*)&fs[(size_t)sid1 * 64 + f0];
        for (int t = 0; t < nt; ++t) {
            int eoff = 4 * t + q;
            bool valid = eoff < cl;
            float4 cur = bf4_to_f4(rowA);
            rowA = rowB;
            int e2 = 4 * (t + 2) + q;
            int sid2 = __shfl(sv, e2 & 63, 64);
            if (e2 < cl) rowB = *(const ushort4*)&fs[(size_t)sid2 * 64 + f0];  // prefetch
            float vx = cur.x + fd4.x, vy = cur.y + fd4.y;
            float vz = cur.z + fd4.z, vw = cur.w + fd4.w;
            vx = fmaxf(vx, NEG_SLOPE * vx);
            vy = fmaxf(vy, NEG_SLOPE * vy);
            vz = fmaxf(vz, NEG_SLOPE * vz);
            vw = fmaxf(vw, NEG_SLOPE * vw);
            float sp = fmaf(a4.x, vx, fmaf(a4.y, vy, fmaf(a4.z, vz, a4.w * vw)));
            sp += __shfl_xor(sp, 1, 64);
            sp += __shfl_xor(sp, 2, 64);
            sp += __shfl_xor(sp, 4, 64);
            sp += __shfl_xor(sp, 8, 64);
            float w = valid ? fast_exp2(sp) : 0.f;  // no-max softmax: shift-invariant
            d += w;
            acc.x = fmaf(w, cur.x, acc.x);
            acc.y = fmaf(w, cur.y, acc.y);
            acc.z = fmaf(w, cur.z, acc.z);
            acc.w = fmaf(w, cur.w, acc.w);
        }
    }
    // merge the 4 per-quarter partial sums (pure additions)
    d += __shfl_xor(d, 16, 64);
    d += __shfl_xor(d, 32, 64);
    acc.x += __shfl_xor(acc.x, 16, 64);
    acc.y += __shfl_xor(acc.y, 16, 64);
    acc.z += __shfl_xor(acc.z, 16, 64);
    acc.w += __shfl_xor(acc.w, 16, 64);
    acc.x += __shfl_xor(acc.x, 32, 64);
    acc.y += __shfl_xor(acc.y, 32, 64);
    acc.z += __shfl_xor(acc.z, 32, 64);
    acc.w += __shfl_xor(acc.w, 32, 64);
    float inv = (d > 0.f) ? 1.f / d : 0.f;
    acc.x *= inv;
    acc.y *= inv;
    acc.z *= inv;
    acc.w *= inv;
    // transpose to lane=feature layout via LDS (same-wave, ordered)
    if (q == 0) *(float4*)&xpose[wv][f0] = acc;
    float val = xpose[wv][lane];
    // layernorm + exact gelu + residual, one feature per lane
    float mean = wave_sum64(val) * 0.015625f;
    float dev = val - mean;
    float var = wave_sum64(dev * dev) * 0.015625f;
    float rstd = rsqrtf(var + LN_EPS);
    float tval = fmaf(dev * rstd, gL, bL);
    float g = 0.5f * tval * (1.f + erff(tval * 0.70710678118654752f));
    h[(size_t)n * 64 + lane] = hval + g;
}

// ---------------- output projection [n,64] @ [64,8] + b ----------------
__global__ void out_proj_kernel(const float* __restrict__ h, const float* __restrict__ W,
                                const float* __restrict__ b, float* __restrict__ out) {
    __shared__ float Ws[64 * 8];
    __shared__ float bs[8];
    __shared__ float Hs[32][65];
    int t = threadIdx.x;
    for (int i = t; i < 512; i += 256) Ws[i] = W[i];
    if (t < 8) bs[t] = b[t];
    int n0 = blockIdx.x * 32;
    for (int i = t; i < 32 * 64; i += 256) {
        int r = i >> 6, c = i & 63;
        int n = n0 + r;
        Hs[r][c] = (n < N_NODES) ? h[(size_t)n * 64 + c] : 0.f;
    }
    __syncthreads();
    int nl = t >> 3, o = t & 7;
    int n = n0 + nl;
    if (n >= N_NODES) return;
    float acc = bs[o];
#pragma unroll
    for (int k = 0; k < 64; ++k) acc = fmaf(Hs[nl][k], Ws[k * 8 + o], acc);
    out[(size_t)n * 8 + o] = acc;
}

extern "C" void kernel_launch(void* const* d_in, const int* in_sizes, int n_in,
                              void* d_out, int out_size, void* d_ws, size_t ws_size,
                              hipStream_t stream) {
    const float* nodes = (const float*)d_in[0];
    const int* src = (const int*)d_in[1];
    const int* dst = (const int*)d_in[2];
    const float* w_in = (const float*)d_in[3];
    const float* b_in = (const float*)d_in[4];
    const float* w_src = (const float*)d_in[5];
    const float* b_src = (const float*)d_in[6];
    const float* w_dst = (const float*)d_in[7];
    const float* b_dst = (const float*)d_in[8];
    const float* attn = (const float*)d_in[9];
    const float* gamma = (const float*)d_in[10];
    const float* beta = (const float*)d_in[11];
    const float* w_out = (const float*)d_in[12];
    const float* b_out = (const float*)d_in[13];
    float* out = (float*)d_out;

    char* ws = (char*)d_ws;
    size_t off = 0;
    auto alloc = [&](size_t bytes) {
        void* p = ws + off;
        off += (bytes + 255) & ~(size_t)255;
        return p;
    };
    float* h = (float*)alloc((size_t)N_NODES * 64 * 4);
    unsigned short* fs = (unsigned short*)alloc((size_t)N_NODES * 64 * 2);
    unsigned short* fd = (unsigned short*)alloc((size_t)N_NODES * 64 * 2);
    unsigned short* wpk_hi = (unsigned short*)alloc((size_t)13 * 4096 * 2);
    unsigned short* wpk_lo = (unsigned short*)alloc((size_t)13 * 4096 * 2);
    int* deg = (int*)alloc((size_t)N_NODES * 4);
    int* row_ptr = (int*)alloc((size_t)(N_NODES + 1) * 4);
    int* pos = (int*)alloc((size_t)N_NODES * 4);
    int* srcs = (int*)alloc((size_t)N_EDGES * 4);
    int* bsum = (int*)alloc((size_t)NSCAN_BLOCKS * 4);

    // CSR by dst, identity node order
    hipMemsetAsync(deg, 0, (size_t)N_NODES * 4, stream);
    count_deg<<<(N_EDGES + 255) / 256, 256, 0, stream>>>(dst, deg);
    scan1<<<NSCAN_BLOCKS, SCAN_B, 0, stream>>>(deg, row_ptr, bsum);
    scan3<<<NSCAN_BLOCKS, SCAN_B, 0, stream>>>(row_ptr, bsum, pos);
    scatter_edges<<<(N_EDGES + 255) / 256, 256, 0, stream>>>(dst, src, pos, srcs);

    // weight packing
    pack_w<<<13, 256, 0, stream>>>(w_in, w_src, w_dst, wpk_hi, wpk_lo);

    // input projection + fused layer-0 dual projection
    mfma_in_proj<<<(N_NODES + 63) / 64, 256, 0, stream>>>(
        nodes, wpk_hi, wpk_lo, b_in, h, wpk_hi + (size_t)1 * 4096, wpk_lo + (size_t)1 * 4096,
        b_src, wpk_hi + (size_t)7 * 4096, wpk_lo + (size_t)7 * 4096, b_dst, fs, fd);

    for (int l = 0; l < NLAYERS; ++l) {
        node_fused_kernel<<<(N_NODES + WPB - 1) / WPB, 256, 0, stream>>>(
            fs, fd, row_ptr, srcs, attn + (size_t)l * 64, gamma + (size_t)l * 64,
            beta + (size_t)l * 64, h);
        if (l + 1 < NLAYERS) {
            mfma_dual<<<(N_NODES + 127) / 128, 256, 0, stream>>>(
                h, wpk_hi + (size_t)(2 + l) * 4096, wpk_lo + (size_t)(2 + l) * 4096,
                b_src + (size_t)(l + 1) * 64, wpk_hi + (size_t)(8 + l) * 4096,
                wpk_lo + (size_t)(8 + l) * 4096, b_dst + (size_t)(l + 1) * 64, fs, fd);
        }
    }

    out_proj_kernel<<<(N_NODES + 31) / 32, 256, 0, stream>>>(h, w_out, b_out, out);
}

// Round 25
// 339.381 us; speedup vs baseline: 1.0174x; 1.0174x over previous
//
#include <hip/hip_runtime.h>
#include <math.h>

#define N_NODES 50000
#define N_EDGES 500000
#define NLAYERS 6
#define NEG_SLOPE 0.2f
#define LN_EPS 1e-5f
#define SCAN_B 1024
#define NSCAN_BLOCKS ((N_NODES + SCAN_B - 1) / SCAN_B)  // 49
#define LOG2E 1.4426950408889634f

typedef __attribute__((ext_vector_type(8))) short short8;
typedef __attribute__((ext_vector_type(4))) float f32x4;

__device__ __forceinline__ float wave_sum64(float v) {
#pragma unroll
    for (int m = 32; m >= 1; m >>= 1) v += __shfl_xor(v, m, 64);
    return v;
}

__device__ __forceinline__ int wave_incl_scan(int v, int lane) {
#pragma unroll
    for (int offs = 1; offs < 64; offs <<= 1) {
        int t = __shfl_up(v, offs, 64);
        if (lane >= offs) v += t;
    }
    return v;
}

__device__ __forceinline__ unsigned bf16_rne(float v) {
    unsigned u = __float_as_uint(v);
    return (u + 0x7fffu + ((u >> 16) & 1u)) >> 16;
}

__device__ __forceinline__ float fast_exp2(float x) {
    float r;
    asm("v_exp_f32 %0, %1" : "=v"(r) : "v"(x));
    return r;
}

__device__ __forceinline__ float4 bf4_to_f4(ushort4 u) {
    float4 r;
    r.x = __uint_as_float((unsigned)u.x << 16);
    r.y = __uint_as_float((unsigned)u.y << 16);
    r.z = __uint_as_float((unsigned)u.z << 16);
    r.w = __uint_as_float((unsigned)u.w << 16);
    return r;
}

// ---------------- CSR build (identity node order) ----------------
__global__ void count_deg(const int* __restrict__ dst, int* __restrict__ deg) {
    int i = blockIdx.x * blockDim.x + threadIdx.x;
    if (i < N_EDGES) atomicAdd(&deg[dst[i]], 1);
}

__global__ void scan1(const int* __restrict__ deg, int* __restrict__ row_ptr,
                      int* __restrict__ bsum) {
    __shared__ int wtot[16];
    int t = threadIdx.x;
    int i = blockIdx.x * SCAN_B + t;
    int lane = t & 63, wv = t >> 6;
    int v = (i < N_NODES) ? deg[i] : 0;
    int incl = wave_incl_scan(v, lane);
    if (lane == 63) wtot[wv] = incl;
    __syncthreads();
    if (wv == 0) {
        int wval = (lane < 16) ? wtot[lane] : 0;
        int ws = wave_incl_scan(wval, lane);
        if (lane < 16) wtot[lane] = ws - wval;
    }
    __syncthreads();
    int excl = incl - v + wtot[wv];
    if (i < N_NODES) row_ptr[i] = excl;
    if (t == SCAN_B - 1) bsum[blockIdx.x] = excl + v;
}

__global__ void scan3(int* __restrict__ row_ptr, const int* __restrict__ bsum,
                      int* __restrict__ pos) {
    __shared__ int boff_s;
    int t = threadIdx.x;
    if (t < 64) {
        int v = (t < NSCAN_BLOCKS && t < (int)blockIdx.x) ? bsum[t] : 0;
#pragma unroll
        for (int m = 32; m >= 1; m >>= 1) v += __shfl_xor(v, m, 64);
        if (t == 0) boff_s = v;
    }
    __syncthreads();
    int i = blockIdx.x * SCAN_B + t;
    if (i < N_NODES) {
        int r = row_ptr[i] + boff_s;
        row_ptr[i] = r;
        pos[i] = r;
    }
    if (i == 0) row_ptr[N_NODES] = N_EDGES;
}

__global__ void scatter_edges(const int* __restrict__ dst, const int* __restrict__ src,
                              int* __restrict__ pos, int* __restrict__ srcs) {
    int i = blockIdx.x * blockDim.x + threadIdx.x;
    if (i < N_EDGES) {
        int p = atomicAdd(&pos[dst[i]], 1);
        srcs[p] = src[i];
    }
}

// ---------------- pack 13 64x64 weight matrices into MFMA B-fragment order -------------
__global__ void pack_w(const float* __restrict__ w_in, const float* __restrict__ w_src,
                       const float* __restrict__ w_dst, unsigned short* __restrict__ wpk_hi,
                       unsigned short* __restrict__ wpk_lo) {
    int b = blockIdx.x;
    const float* W = (b == 0) ? w_in
                              : (b <= 6 ? w_src + (size_t)(b - 1) * 4096
                                        : w_dst + (size_t)(b - 7) * 4096);
    unsigned short* hi = wpk_hi + (size_t)b * 4096;
    unsigned short* lo = wpk_lo + (size_t)b * 4096;
    for (int idx = threadIdx.x; idx < 4096; idx += 256) {
        int t = idx >> 10;
        int s = (idx >> 9) & 1;
        int l = (idx >> 3) & 63;
        int j = idx & 7;
        int row = s * 32 + (l >> 4) * 8 + j;
        int col = t * 16 + (l & 15);
        float v = W[row * 64 + col];
        unsigned rh = bf16_rne(v);
        float hf = __uint_as_float(rh << 16);
        unsigned rl = bf16_rne(v - hf);
        hi[idx] = (unsigned short)rh;
        lo[idx] = (unsigned short)rl;
    }
}

// load 8 fp32 and split into bf16 hi/lo fragments (global or LDS pointer)
__device__ __forceinline__ void load_split8(const float* p, short8& hi, short8& lo) {
    float4 x0 = *(const float4*)p;
    float4 x1 = *(const float4*)(p + 4);
    float v[8] = {x0.x, x0.y, x0.z, x0.w, x1.x, x1.y, x1.z, x1.w};
#pragma unroll
    for (int j = 0; j < 8; ++j) {
        unsigned rh = bf16_rne(v[j]);
        float hf = __uint_as_float(rh << 16);
        unsigned rl = bf16_rne(v[j] - hf);
        hi[j] = (short)rh;
        lo[j] = (short)rl;
    }
}

// 16 output rows x 64 cols via 3-MFMA split-bf16 (fp32-accurate)
__device__ __forceinline__ void mfma_16rows(const short8 ah0, const short8 ah1, const short8 al0,
                                            const short8 al1,
                                            const unsigned short* __restrict__ whi,
                                            const unsigned short* __restrict__ wlo, int lane,
                                            f32x4 acc[4]) {
#pragma unroll
    for (int t = 0; t < 4; ++t) {
#pragma unroll
        for (int s = 0; s < 2; ++s) {
            const size_t boff = ((size_t)((t * 2 + s) * 64 + lane)) * 8;
            short8 bh = *(const short8*)(whi + boff);
            short8 bl = *(const short8*)(wlo + boff);
            short8 a_h = s ? ah1 : ah0;
            short8 a_l = s ? al1 : al0;
            acc[t] = __builtin_amdgcn_mfma_f32_16x16x32_bf16(a_h, bh, acc[t], 0, 0, 0);
            acc[t] = __builtin_amdgcn_mfma_f32_16x16x32_bf16(a_l, bh, acc[t], 0, 0, 0);
            acc[t] = __builtin_amdgcn_mfma_f32_16x16x32_bf16(a_h, bl, acc[t], 0, 0, 0);
        }
    }
}

// ---------------- input projection + FUSED layer-0 dual projection (proven) ------------
__global__ void mfma_in_proj(const float* __restrict__ X,
                             const unsigned short* __restrict__ whi,
                             const unsigned short* __restrict__ wlo,
                             const float* __restrict__ bias, float* __restrict__ H,
                             const unsigned short* __restrict__ wshi,
                             const unsigned short* __restrict__ wslo,
                             const float* __restrict__ bs,
                             const unsigned short* __restrict__ wdhi,
                             const unsigned short* __restrict__ wdlo,
                             const float* __restrict__ bd, unsigned short* __restrict__ FS,
                             float* __restrict__ FD) {
    __shared__ float tr[4][16 * 64];
    int lane = threadIdx.x & 63, wv = threadIdx.x >> 6;
    int R = blockIdx.x * 64 + wv * 16;
    int arow = min(R + (lane & 15), N_NODES - 1);
    const float* p = X + (size_t)arow * 64 + (lane >> 4) * 8;
    short8 ah0, ah1, al0, al1;
    load_split8(p, ah0, al0);
    load_split8(p + 32, ah1, al1);
    f32x4 acc[4];
    f32x4 z = {0.f, 0.f, 0.f, 0.f};
#pragma unroll
    for (int t = 0; t < 4; ++t) acc[t] = z;
    mfma_16rows(ah0, ah1, al0, al1, whi, wlo, lane, acc);
    int crow = R + (lane >> 4) * 4;
    int lrow0 = (lane >> 4) * 4;
#pragma unroll
    for (int t = 0; t < 4; ++t) {
        int col = t * 16 + (lane & 15);
        float bv = bias[col];
#pragma unroll
        for (int r = 0; r < 4; ++r) {
            int row = crow + r;
            float v = acc[t][r] + bv;
            if (row < N_NODES) H[(size_t)row * 64 + col] = v;
            tr[wv][(lrow0 + r) * 64 + col] = v;  // wave-private LDS transpose
        }
    }
    load_split8(&tr[wv][(lane & 15) * 64 + (lane >> 4) * 8], ah0, al0);
    load_split8(&tr[wv][(lane & 15) * 64 + 32 + (lane >> 4) * 8], ah1, al1);
    f32x4 accS[4], accD[4];
#pragma unroll
    for (int t = 0; t < 4; ++t) {
        accS[t] = z;
        accD[t] = z;
    }
    mfma_16rows(ah0, ah1, al0, al1, wshi, wslo, lane, accS);
    mfma_16rows(ah0, ah1, al0, al1, wdhi, wdlo, lane, accD);
#pragma unroll
    for (int t = 0; t < 4; ++t) {
        int col = t * 16 + (lane & 15);
        float bsv = bs[col], bdv = bd[col];
#pragma unroll
        for (int r = 0; r < 4; ++r) {
            int row = crow + r;
            if (row < N_NODES) {
                FS[(size_t)row * 64 + col] = (unsigned short)bf16_rne(accS[t][r] + bsv);
                FD[(size_t)row * 64 + col] = accD[t][r] + bdv;
            }
        }
    }
}

// ---------------- dual projection, 2 C-tiles per wave, shared B-fragment loads ---------
__global__ void mfma_dual(const float* __restrict__ X, const unsigned short* __restrict__ wshi,
                          const unsigned short* __restrict__ wslo, const float* __restrict__ bs,
                          const unsigned short* __restrict__ wdhi,
                          const unsigned short* __restrict__ wdlo, const float* __restrict__ bd,
                          unsigned short* __restrict__ FS, float* __restrict__ FD) {
    int lane = threadIdx.x & 63, wv = threadIdx.x >> 6;
    int R = blockIdx.x * 128 + wv * 32;
    int arow0 = min(R + (lane & 15), N_NODES - 1);
    int arow1 = min(R + 16 + (lane & 15), N_NODES - 1);
    const float* p0 = X + (size_t)arow0 * 64 + (lane >> 4) * 8;
    const float* p1 = X + (size_t)arow1 * 64 + (lane >> 4) * 8;
    short8 a0h0, a0h1, a0l0, a0l1, a1h0, a1h1, a1l0, a1l1;
    load_split8(p0, a0h0, a0l0);
    load_split8(p0 + 32, a0h1, a0l1);
    load_split8(p1, a1h0, a1l0);
    load_split8(p1 + 32, a1h1, a1l1);
    f32x4 aS0[4], aD0[4], aS1[4], aD1[4];
    f32x4 z = {0.f, 0.f, 0.f, 0.f};
#pragma unroll
    for (int t = 0; t < 4; ++t) {
        aS0[t] = z;
        aD0[t] = z;
        aS1[t] = z;
        aD1[t] = z;
    }
#pragma unroll
    for (int t = 0; t < 4; ++t) {
#pragma unroll
        for (int s = 0; s < 2; ++s) {
            const size_t boff = ((size_t)((t * 2 + s) * 64 + lane)) * 8;
            short8 bsh = *(const short8*)(wshi + boff);
            short8 bsl = *(const short8*)(wslo + boff);
            short8 bdh = *(const short8*)(wdhi + boff);
            short8 bdl = *(const short8*)(wdlo + boff);
            short8 A0h = s ? a0h1 : a0h0, A0l = s ? a0l1 : a0l0;
            short8 A1h = s ? a1h1 : a1h0, A1l = s ? a1l1 : a1l0;
            aS0[t] = __builtin_amdgcn_mfma_f32_16x16x32_bf16(A0h, bsh, aS0[t], 0, 0, 0);
            aS0[t] = __builtin_amdgcn_mfma_f32_16x16x32_bf16(A0l, bsh, aS0[t], 0, 0, 0);
            aS0[t] = __builtin_amdgcn_mfma_f32_16x16x32_bf16(A0h, bsl, aS0[t], 0, 0, 0);
            aS1[t] = __builtin_amdgcn_mfma_f32_16x16x32_bf16(A1h, bsh, aS1[t], 0, 0, 0);
            aS1[t] = __builtin_amdgcn_mfma_f32_16x16x32_bf16(A1l, bsh, aS1[t], 0, 0, 0);
            aS1[t] = __builtin_amdgcn_mfma_f32_16x16x32_bf16(A1h, bsl, aS1[t], 0, 0, 0);
            aD0[t] = __builtin_amdgcn_mfma_f32_16x16x32_bf16(A0h, bdh, aD0[t], 0, 0, 0);
            aD0[t] = __builtin_amdgcn_mfma_f32_16x16x32_bf16(A0l, bdh, aD0[t], 0, 0, 0);
            aD0[t] = __builtin_amdgcn_mfma_f32_16x16x32_bf16(A0h, bdl, aD0[t], 0, 0, 0);
            aD1[t] = __builtin_amdgcn_mfma_f32_16x16x32_bf16(A1h, bdh, aD1[t], 0, 0, 0);
            aD1[t] = __builtin_amdgcn_mfma_f32_16x16x32_bf16(A1l, bdh, aD1[t], 0, 0, 0);
            aD1[t] = __builtin_amdgcn_mfma_f32_16x16x32_bf16(A1h, bdl, aD1[t], 0, 0, 0);
        }
    }
    int crow0 = R + (lane >> 4) * 4;
    int crow1 = R + 16 + (lane >> 4) * 4;
#pragma unroll
    for (int t = 0; t < 4; ++t) {
        int col = t * 16 + (lane & 15);
        float bsv = bs[col], bdv = bd[col];
#pragma unroll
        for (int r = 0; r < 4; ++r) {
            int row0 = crow0 + r;
            if (row0 < N_NODES) {
                FS[(size_t)row0 * 64 + col] = (unsigned short)bf16_rne(aS0[t][r] + bsv);
                FD[(size_t)row0 * 64 + col] = aD0[t][r] + bdv;
            }
            int row1 = crow1 + r;
            if (row1 < N_NODES) {
                FS[(size_t)row1 * 64 + col] = (unsigned short)bf16_rne(aS1[t][r] + bsv);
                FD[(size_t)row1 * 64 + col] = aD1[t][r] + bdv;
            }
        }
    }
}

// ---------------- fused per-node: quarter-wave, no-max softmax (round-23 optimum) ------
#define WPB 4  // waves per block, 1 node per wave
__global__ void node_fused_kernel(const unsigned short* __restrict__ fs,
                                  const float* __restrict__ fd, const int* __restrict__ row_ptr,
                                  const int* __restrict__ srcs, const float* __restrict__ attn,
                                  const float* __restrict__ gamma, const float* __restrict__ beta,
                                  float* __restrict__ h) {
    __shared__ float xpose[WPB][64];
    int lane = threadIdx.x & 63;
    int wv = threadIdx.x >> 6;
    int q = lane >> 4;
    int ql = lane & 15;
    int f0 = ql << 2;
    int n = blockIdx.x * WPB + wv;
    if (n >= N_NODES) return;
    float gL = gamma[lane], bL = beta[lane];
    float hval = h[(size_t)n * 64 + lane];  // coalesced stream
    float4 a4 = *(const float4*)&attn[f0];
    a4.x *= LOG2E;
    a4.y *= LOG2E;
    a4.z *= LOG2E;
    a4.w *= LOG2E;
    int beg = row_ptr[n], end = row_ptr[n + 1];
    int deg = end - beg;
    float4 fd4 = *(const float4*)&fd[(size_t)n * 64 + f0];
    float d = 0.f;
    float4 acc = make_float4(0.f, 0.f, 0.f, 0.f);
    for (int c0 = 0; c0 < deg; c0 += 64) {
        int cl = min(64, deg - c0);
        int sv = (lane < cl) ? srcs[beg + c0 + lane] : 0;
        int nt = (cl + 3) >> 2;
        ushort4 rowA = make_ushort4(0, 0, 0, 0), rowB = rowA;
        int sid0 = __shfl(sv, q, 64);
        if (q < cl) rowA = *(const ushort4*)&fs[(size_t)sid0 * 64 + f0];
        int sid1 = __shfl(sv, (4 + q) & 63, 64);
        if (4 + q < cl) rowB = *(const ushort4*)&fs[(size_t)sid1 * 64 + f0];
        for (int t = 0; t < nt; ++t) {
            int eoff = 4 * t + q;
            bool valid = eoff < cl;
            float4 cur = bf4_to_f4(rowA);
            rowA = rowB;
            int e2 = 4 * (t + 2) + q;
            int sid2 = __shfl(sv, e2 & 63, 64);
            if (e2 < cl) rowB = *(const ushort4*)&fs[(size_t)sid2 * 64 + f0];  // prefetch
            float vx = cur.x + fd4.x, vy = cur.y + fd4.y;
            float vz = cur.z + fd4.z, vw = cur.w + fd4.w;
            vx = fmaxf(vx, NEG_SLOPE * vx);
            vy = fmaxf(vy, NEG_SLOPE * vy);
            vz = fmaxf(vz, NEG_SLOPE * vz);
            vw = fmaxf(vw, NEG_SLOPE * vw);
            float sp = fmaf(a4.x, vx, fmaf(a4.y, vy, fmaf(a4.z, vz, a4.w * vw)));
            sp += __shfl_xor(sp, 1, 64);
            sp += __shfl_xor(sp, 2, 64);
            sp += __shfl_xor(sp, 4, 64);
            sp += __shfl_xor(sp, 8, 64);
            float w = valid ? fast_exp2(sp) : 0.f;  // no-max softmax: shift-invariant
            d += w;
            acc.x = fmaf(w, cur.x, acc.x);
            acc.y = fmaf(w, cur.y, acc.y);
            acc.z = fmaf(w, cur.z, acc.z);
            acc.w = fmaf(w, cur.w, acc.w);
        }
    }
    // merge the 4 per-quarter partial sums (pure additions)
    d += __shfl_xor(d, 16, 64);
    d += __shfl_xor(d, 32, 64);
    acc.x += __shfl_xor(acc.x, 16, 64);
    acc.y += __shfl_xor(acc.y, 16, 64);
    acc.z += __shfl_xor(acc.z, 16, 64);
    acc.w += __shfl_xor(acc.w, 16, 64);
    acc.x += __shfl_xor(acc.x, 32, 64);
    acc.y += __shfl_xor(acc.y, 32, 64);
    acc.z += __shfl_xor(acc.z, 32, 64);
    acc.w += __shfl_xor(acc.w, 32, 64);
    float inv = (d > 0.f) ? 1.f / d : 0.f;
    acc.x *= inv;
    acc.y *= inv;
    acc.z *= inv;
    acc.w *= inv;
    // transpose to lane=feature layout via LDS (same-wave, ordered)
    if (q == 0) *(float4*)&xpose[wv][f0] = acc;
    float val = xpose[wv][lane];
    // layernorm + exact gelu + residual, one feature per lane
    float mean = wave_sum64(val) * 0.015625f;
    float dev = val - mean;
    float var = wave_sum64(dev * dev) * 0.015625f;
    float rstd = rsqrtf(var + LN_EPS);
    float tval = fmaf(dev * rstd, gL, bL);
    float g = 0.5f * tval * (1.f + erff(tval * 0.70710678118654752f));
    h[(size_t)n * 64 + lane] = hval + g;
}

// ---------------- output projection [n,64] @ [64,8] + b ----------------
__global__ void out_proj_kernel(const float* __restrict__ h, const float* __restrict__ W,
                                const float* __restrict__ b, float* __restrict__ out) {
    __shared__ float Ws[64 * 8];
    __shared__ float bs[8];
    __shared__ float Hs[32][65];
    int t = threadIdx.x;
    for (int i = t; i < 512; i += 256) Ws[i] = W[i];
    if (t < 8) bs[t] = b[t];
    int n0 = blockIdx.x * 32;
    for (int i = t; i < 32 * 64; i += 256) {
        int r = i >> 6, c = i & 63;
        int n = n0 + r;
        Hs[r][c] = (n < N_NODES) ? h[(size_t)n * 64 + c] : 0.f;
    }
    __syncthreads();
    int nl = t >> 3, o = t & 7;
    int n = n0 + nl;
    if (n >= N_NODES) return;
    float acc = bs[o];
#pragma unroll
    for (int k = 0; k < 64; ++k) acc = fmaf(Hs[nl][k], Ws[k * 8 + o], acc);
    out[(size_t)n * 8 + o] = acc;
}

extern "C" void kernel_launch(void* const* d_in, const int* in_sizes, int n_in,
                              void* d_out, int out_size, void* d_ws, size_t ws_size,
                              hipStream_t stream) {
    const float* nodes = (const float*)d_in[0];
    const int* src = (const int*)d_in[1];
    const int* dst = (const int*)d_in[2];
    const float* w_in = (const float*)d_in[3];
    const float* b_in = (const float*)d_in[4];
    const float* w_src = (const float*)d_in[5];
    const float* b_src = (const float*)d_in[6];
    const float* w_dst = (const float*)d_in[7];
    const float* b_dst = (const float*)d_in[8];
    const float* attn = (const float*)d_in[9];
    const float* gamma = (const float*)d_in[10];
    const float* beta = (const float*)d_in[11];
    const float* w_out = (const float*)d_in[12];
    const float* b_out = (const float*)d_in[13];
    float* out = (float*)d_out;

    char* ws = (char*)d_ws;
    size_t off = 0;
    auto alloc = [&](size_t bytes) {
        void* p = ws + off;
        off += (bytes + 255) & ~(size_t)255;
        return p;
    };
    float* h = (float*)alloc((size_t)N_NODES * 64 * 4);
    unsigned short* fs = (unsigned short*)alloc((size_t)N_NODES * 64 * 2);
    float* fd = (float*)alloc((size_t)N_NODES * 64 * 4);
    unsigned short* wpk_hi = (unsigned short*)alloc((size_t)13 * 4096 * 2);
    unsigned short* wpk_lo = (unsigned short*)alloc((size_t)13 * 4096 * 2);
    int* deg = (int*)alloc((size_t)N_NODES * 4);
    int* row_ptr = (int*)alloc((size_t)(N_NODES + 1) * 4);
    int* pos = (int*)alloc((size_t)N_NODES * 4);
    int* srcs = (int*)alloc((size_t)N_EDGES * 4);
    int* bsum = (int*)alloc((size_t)NSCAN_BLOCKS * 4);

    // CSR by dst, identity node order
    hipMemsetAsync(deg, 0, (size_t)N_NODES * 4, stream);
    count_deg<<<(N_EDGES + 255) / 256, 256, 0, stream>>>(dst, deg);
    scan1<<<NSCAN_BLOCKS, SCAN_B, 0, stream>>>(deg, row_ptr, bsum);
    scan3<<<NSCAN_BLOCKS, SCAN_B, 0, stream>>>(row_ptr, bsum, pos);
    scatter_edges<<<(N_EDGES + 255) / 256, 256, 0, stream>>>(dst, src, pos, srcs);

    // weight packing
    pack_w<<<13, 256, 0, stream>>>(w_in, w_src, w_dst, wpk_hi, wpk_lo);

    // input projection + fused layer-0 dual projection
    mfma_in_proj<<<(N_NODES + 63) / 64, 256, 0, stream>>>(
        nodes, wpk_hi, wpk_lo, b_in, h, wpk_hi + (size_t)1 * 4096, wpk_lo + (size_t)1 * 4096,
        b_src, wpk_hi + (size_t)7 * 4096, wpk_lo + (size_t)7 * 4096, b_dst, fs, fd);

    for (int l = 0; l < NLAYERS; ++l) {
        node_fused_kernel<<<(N_NODES + WPB - 1) / WPB, 256, 0, stream>>>(
            fs, fd, row_ptr, srcs, attn + (size_t)l * 64, gamma + (size_t)l * 64,
            beta + (size_t)l * 64, h);
        if (l + 1 < NLAYERS) {
            mfma_dual<<<(N_NODES + 127) / 128, 256, 0, stream>>>(
                h, wpk_hi + (size_t)(2 + l) * 4096, wpk_lo + (size_t)(2 + l) * 4096,
                b_src + (size_t)(l + 1) * 64, wpk_hi + (size_t)(8 + l) * 4096,
                wpk_lo + (size_t)(8 + l) * 4096, b_dst + (size_t)(l + 1) * 64, fs, fd);
        }
    }

    out_proj_kernel<<<(N_NODES + 31) / 32, 256, 0, stream>>>(h, w_out, b_out, out);
}